// Round 9
// baseline (540.700 us; speedup 1.0000x reference)
//
#include <hip/hip_runtime.h>

#define N_NODES 100000
#define N_EDGES 1600000
#define CH      128
#define OUT_CH  64
#define NUM_G   64
#define NREP    8           // gsums replicas (agg_pool atomics)
#define CAP     64          // fixed CSR slots per node (P(deg>64) ~ 2e-18)

typedef unsigned short ushort_t;
typedef unsigned int uint_t;
typedef __attribute__((ext_vector_type(8))) short short8;
typedef __attribute__((ext_vector_type(4))) float f32x4;

#define WB 64               // cvt_w blocks per weight (128*128/256)
#define EB 6250             // edge blocks, 1 edge/thread (prep)
#define GB ((N_NODES + 63) / 64)     // gemm1 row-blocks (64 rows/block)
#define GB2 ((N_NODES + 127) / 128)  // lds-gemm row-blocks (128 rows/block)
#define AB ((N_NODES + 3) / 4)       // agg node-quads (4 nodes/block)
#define AB2 (AB * 2)                 // channel-split agg_pool blocks
#define DB 98               // dinv blocks (ceil(100000/1024))

__device__ __forceinline__ ushort_t f2b(float f) {
    union { float f; uint_t i; } v; v.f = f;
    uint_t u = v.i;
    uint_t r = (u + 0x7fffu + ((u >> 16) & 1u)) >> 16;
    return (ushort_t)r;
}
__device__ __forceinline__ float blo(uint_t u) {
    union { uint_t i; float f; } v; v.i = u << 16; return v.f;
}
__device__ __forceinline__ float bhi(uint_t u) {
    union { uint_t i; float f; } v; v.i = u & 0xffff0000u; return v.f;
}

// ---------------- tiny pre-kernel: W1/W2/W3 f32 -> bf16 transposed -----------
__global__ __launch_bounds__(256) void cvtw_kernel(const float* __restrict__ W1,
                                                   const float* __restrict__ W2,
                                                   const float* __restrict__ W3,
                                                   ushort_t* __restrict__ Wt1,
                                                   ushort_t* __restrict__ Wt2,
                                                   ushort_t* __restrict__ Wt3) {
    int wi = blockIdx.x / WB;
    const float* W  = (wi == 0) ? W1 : (wi == 1) ? W2 : W3;
    ushort_t*   Wt = (wi == 0) ? Wt1 : (wi == 1) ? Wt2 : Wt3;
    int t = (blockIdx.x % WB) * 256 + threadIdx.x;
    int k = t >> 7, n = t & 127;
    Wt[(size_t)n * CH + k] = f2b(W[t]);
}

// ---------------- MFMA GEMM body, global-Wt flavor --------------------------
template <bool F32A>
__device__ __forceinline__ void gemm_body(int bid, int tid,
                                          const void* __restrict__ A,
                                          const ushort_t* __restrict__ Wt,
                                          const float* __restrict__ bias,
                                          ushort_t* __restrict__ H) {
    int wv = tid >> 6, lane = tid & 63;
    int q = lane >> 4, ml = lane & 15;
    int r0 = bid * 64 + wv * 16;
    int arow = r0 + ml;
    if (arow >= N_NODES) arow = N_NODES - 1;  // clamp; stores guarded

    f32x4 acc[8];
#pragma unroll
    for (int ct = 0; ct < 8; ++ct) { acc[ct][0] = 0.f; acc[ct][1] = 0.f; acc[ct][2] = 0.f; acc[ct][3] = 0.f; }

#pragma unroll
    for (int ks = 0; ks < 4; ++ks) {
        short8 af;
        if constexpr (F32A) {
            const float* ap = (const float*)A + (size_t)arow * CH + ks * 32 + q * 8;
            f32x4 v0 = *(const f32x4*)ap;
            f32x4 v1 = *(const f32x4*)(ap + 4);
#pragma unroll
            for (int j = 0; j < 4; ++j) {
                af[j]     = (short)f2b(v0[j]);
                af[j + 4] = (short)f2b(v1[j]);
            }
        } else {
            const ushort_t* ap = (const ushort_t*)A + (size_t)arow * CH + ks * 32 + q * 8;
            af = *(const short8*)ap;
        }
#pragma unroll
        for (int ct = 0; ct < 8; ++ct) {
            short8 bf = *(const short8*)(Wt + (size_t)(ct * 16 + ml) * CH + ks * 32 + q * 8);
            acc[ct] = __builtin_amdgcn_mfma_f32_16x16x32_bf16(af, bf, acc[ct], 0, 0, 0);
        }
    }

#pragma unroll
    for (int ct = 0; ct < 8; ++ct) {
        int col = ct * 16 + ml;
        float bv = bias[col];
#pragma unroll
        for (int i = 0; i < 4; ++i) {
            int rr = r0 + q * 4 + i;
            if (rr < N_NODES)
                H[(size_t)rr * CH + col] = f2b(acc[ct][i] + bv);
        }
    }
}

// ---------------- fused: direct CSR insert | gemm layer-1 (fp32 A) -----------
// The atomicAdd's return value IS the final slot (fixed CAP=64 segment per
// node), so the scan->fill chain is deleted: one pass builds count AND csr.
__global__ __launch_bounds__(256) void prep_gemm1(const int* __restrict__ src,
                                                  const int* __restrict__ dst,
                                                  int* __restrict__ cnt,
                                                  int* __restrict__ csr_src,
                                                  const float* __restrict__ x,
                                                  const ushort_t* __restrict__ Wt,
                                                  const float* __restrict__ bias,
                                                  ushort_t* __restrict__ H) {
    if (blockIdx.x < EB) {
        int e = blockIdx.x * 256 + threadIdx.x;   // EB*256 == N_EDGES exactly
        int d = dst[e];
        int p = atomicAdd(&cnt[d], 1);
        if (p < CAP) csr_src[(size_t)d * CAP + p] = src[e];
    } else {
        gemm_body<true>(blockIdx.x - EB, threadIdx.x, x, Wt, bias, H);
    }
}

// ---------------- dinv + graph-size histogram (replaces the scan chain) ------
__global__ __launch_bounds__(1024) void dinv_kernel(const int* __restrict__ cnt,
                                                    float* __restrict__ dinv,
                                                    const int* __restrict__ batch,
                                                    int* __restrict__ counts) {
    __shared__ int s_c[NUM_G];
    int tid = threadIdx.x;
    int i = blockIdx.x * 1024 + tid;
    if (tid < NUM_G) s_c[tid] = 0;
    __syncthreads();
    if (i < N_NODES) {
        dinv[i] = rsqrtf((float)cnt[i] + 1.0f);
        atomicAdd(&s_c[batch[i]], 1);
    }
    __syncthreads();
    if (tid < NUM_G) atomicAdd(&counts[tid], s_c[tid]);
}

// ---------------- standalone GEMM: Wt staged in LDS (XOR-swizzled) -----------
__global__ __launch_bounds__(512) void gemm_mfma(const ushort_t* __restrict__ A,
                                                 const ushort_t* __restrict__ Wt,
                                                 const float* __restrict__ bias,
                                                 ushort_t* __restrict__ H) {
    __shared__ ushort_t sW[CH * CH];   // 32 KiB
    int tid = threadIdx.x;
    for (int i = tid; i < CH * CH / 8; i += 512) {   // 2048 x 16B chunks
        int row = i >> 4, slot = i & 15;
        uint4 v = *(const uint4*)(Wt + (size_t)row * CH + slot * 8);
        *(uint4*)(&sW[row * CH + ((slot ^ (row & 7)) * 8)]) = v;
    }
    __syncthreads();

    int wv = tid >> 6, lane = tid & 63;
    int q = lane >> 4, ml = lane & 15;
    int r0 = blockIdx.x * 128 + wv * 16;
    int arow = r0 + ml;
    if (arow >= N_NODES) arow = N_NODES - 1;
    const ushort_t* ap = A + (size_t)arow * CH;

    f32x4 acc[8];
#pragma unroll
    for (int ct = 0; ct < 8; ++ct) { acc[ct][0] = 0.f; acc[ct][1] = 0.f; acc[ct][2] = 0.f; acc[ct][3] = 0.f; }

#pragma unroll
    for (int ks = 0; ks < 4; ++ks) {
        short8 af = *(const short8*)(ap + ks * 32 + q * 8);
        int slot = ks * 4 + q;
#pragma unroll
        for (int ct = 0; ct < 8; ++ct) {
            int srow = ct * 16 + ml;
            short8 bf = *(const short8*)(&sW[srow * CH + ((slot ^ (srow & 7)) * 8)]);
            acc[ct] = __builtin_amdgcn_mfma_f32_16x16x32_bf16(af, bf, acc[ct], 0, 0, 0);
        }
    }

#pragma unroll
    for (int ct = 0; ct < 8; ++ct) {
        int col = ct * 16 + ml;
        float bv = bias[col];
#pragma unroll
        for (int i = 0; i < 4; ++i) {
            int rr = r0 + q * 4 + i;
            if (rr < N_NODES)
                H[(size_t)rr * CH + col] = f2b(acc[ct][i] + bv);
        }
    }
}

// ---------------- UNSPLIT gather body (single <=64-edge chunk) ---------------
// acc = dn*(sum_e dinv[s]*h[s] + dn*h[n]); edge list at node*CAP, len<=64,
// so the chunk loop is gone. 16-lane channel groups x 4 edge slots, 2-deep.
__device__ __forceinline__ void agg_node(int node, int lane, int q, int c8,
                                         const ushort_t* __restrict__ h,
                                         const int* __restrict__ csr_src,
                                         const int* __restrict__ cnt,
                                         const float* __restrict__ dinv,
                                         float (&acc)[8]) {
    int deg = min(cnt[node], CAP);
    float dn = dinv[node];
    uint4 us = *(const uint4*)(h + (size_t)node * CH + c8);   // early self load
#pragma unroll
    for (int i = 0; i < 8; ++i) acc[i] = 0.0f;

    int s = 0; float w = 0.0f;
    if (lane < deg) { s = csr_src[(size_t)node * CAP + lane]; w = dinv[s]; }

    if (deg > 0) {
        int   sj = __shfl(s, q);
        float wj = __shfl(w, q);
        uint4 u  = *(const uint4*)(h + (size_t)sj * CH + c8);

        for (int j0 = 0; j0 < deg; j0 += 4) {
            uint4 un = u; float wn = 0.0f;
            if (j0 + 4 < deg) {
                int sn = __shfl(s, j0 + 4 + q);
                wn = __shfl(w, j0 + 4 + q);
                un = *(const uint4*)(h + (size_t)sn * CH + c8);
            }
            acc[0] = fmaf(wj, blo(u.x), acc[0]);
            acc[1] = fmaf(wj, bhi(u.x), acc[1]);
            acc[2] = fmaf(wj, blo(u.y), acc[2]);
            acc[3] = fmaf(wj, bhi(u.y), acc[3]);
            acc[4] = fmaf(wj, blo(u.z), acc[4]);
            acc[5] = fmaf(wj, bhi(u.z), acc[5]);
            acc[6] = fmaf(wj, blo(u.w), acc[6]);
            acc[7] = fmaf(wj, bhi(u.w), acc[7]);
            u = un; wj = wn;
        }
    }

#pragma unroll
    for (int i = 0; i < 8; ++i) {
        acc[i] += __shfl_xor(acc[i], 16);
        acc[i] += __shfl_xor(acc[i], 32);
    }

    acc[0] = dn * fmaf(dn, blo(us.x), acc[0]);
    acc[1] = dn * fmaf(dn, bhi(us.x), acc[1]);
    acc[2] = dn * fmaf(dn, blo(us.y), acc[2]);
    acc[3] = dn * fmaf(dn, bhi(us.y), acc[3]);
    acc[4] = dn * fmaf(dn, blo(us.z), acc[4]);
    acc[5] = dn * fmaf(dn, bhi(us.z), acc[5]);
    acc[6] = dn * fmaf(dn, blo(us.w), acc[6]);
    acc[7] = dn * fmaf(dn, bhi(us.w), acc[7]);
}

// ---------------- edge aggregation, layers 1&2 (UNSPLIT; bf16 + relu) --------
__global__ __launch_bounds__(256) void agg_bf16(const ushort_t* __restrict__ h,
                                                const int* __restrict__ csr_src,
                                                const int* __restrict__ cnt,
                                                const float* __restrict__ dinv,
                                                ushort_t* __restrict__ outp) {
    int wv = threadIdx.x >> 6, lane = threadIdx.x & 63;
    int node = blockIdx.x * 4 + wv;
    if (node >= N_NODES) return;
    int q = lane >> 4;
    int c8 = (lane & 15) * 8;

    float acc[8];
    agg_node(node, lane, q, c8, h, csr_src, cnt, dinv, acc);

#pragma unroll
    for (int i = 0; i < 8; ++i) acc[i] = fmaxf(acc[i], 0.0f);   // relu

    if (q == 0) {
        uint4 o;
        o.x = (uint_t)f2b(acc[0]) | ((uint_t)f2b(acc[1]) << 16);
        o.y = (uint_t)f2b(acc[2]) | ((uint_t)f2b(acc[3]) << 16);
        o.z = (uint_t)f2b(acc[4]) | ((uint_t)f2b(acc[5]) << 16);
        o.w = (uint_t)f2b(acc[6]) | ((uint_t)f2b(acc[7]) << 16);
        *(uint4*)(outp + (size_t)node * CH + c8) = o;
    }
}

// ---------------- channel-split gather body (agg_pool only) ------------------
// 8-lane channel groups x 8 edge slots; cb = half*64 + (lane&7)*8, cg=lane>>3.
__device__ __forceinline__ void agg_node_h(int node, int lane, int cg, int cb,
                                           const ushort_t* __restrict__ h,
                                           const int* __restrict__ csr_src,
                                           const int* __restrict__ cnt,
                                           const float* __restrict__ dinv,
                                           float (&acc)[8]) {
    int deg = min(cnt[node], CAP);
    float dn = dinv[node];
    uint4 us = *(const uint4*)(h + (size_t)node * CH + cb);   // early self load
#pragma unroll
    for (int i = 0; i < 8; ++i) acc[i] = 0.0f;

    int s = 0; float w = 0.0f;
    if (lane < deg) { s = csr_src[(size_t)node * CAP + lane]; w = dinv[s]; }

    if (deg > 0) {
        int   sj = __shfl(s, cg);
        float wj = __shfl(w, cg);
        uint4 u  = *(const uint4*)(h + (size_t)sj * CH + cb);

        for (int j0 = 0; j0 < deg; j0 += 8) {
            uint4 un = u; float wn = 0.0f;
            if (j0 + 8 < deg) {                    // max shfl idx 56+7=63, safe
                int sn = __shfl(s, j0 + 8 + cg);
                wn = __shfl(w, j0 + 8 + cg);
                un = *(const uint4*)(h + (size_t)sn * CH + cb);
            }
            acc[0] = fmaf(wj, blo(u.x), acc[0]);
            acc[1] = fmaf(wj, bhi(u.x), acc[1]);
            acc[2] = fmaf(wj, blo(u.y), acc[2]);
            acc[3] = fmaf(wj, bhi(u.y), acc[3]);
            acc[4] = fmaf(wj, blo(u.z), acc[4]);
            acc[5] = fmaf(wj, bhi(u.z), acc[5]);
            acc[6] = fmaf(wj, blo(u.w), acc[6]);
            acc[7] = fmaf(wj, bhi(u.w), acc[7]);
            u = un; wj = wn;
        }
    }

#pragma unroll
    for (int i = 0; i < 8; ++i) {          // sum over the 8 edge-slot groups
        acc[i] += __shfl_xor(acc[i], 8);
        acc[i] += __shfl_xor(acc[i], 16);
        acc[i] += __shfl_xor(acc[i], 32);
    }

    acc[0] = dn * fmaf(dn, blo(us.x), acc[0]);
    acc[1] = dn * fmaf(dn, bhi(us.x), acc[1]);
    acc[2] = dn * fmaf(dn, blo(us.y), acc[2]);
    acc[3] = dn * fmaf(dn, bhi(us.y), acc[3]);
    acc[4] = dn * fmaf(dn, blo(us.z), acc[4]);
    acc[5] = dn * fmaf(dn, bhi(us.z), acc[5]);
    acc[6] = dn * fmaf(dn, blo(us.w), acc[6]);
    acc[7] = dn * fmaf(dn, bhi(us.w), acc[7]);
}

__device__ __forceinline__ void split_decode(int b, int wv,
                                             int& half, int& node) {
    half = (b >> 2) & 1;
    int nb = ((b >> 3) << 2) | (b & 3);     // [0, AB)
    node = nb * 4 + wv;
}

// ---------------- layer-3 aggregation fused with mean-pool (SPLIT) -----------
// 1 atomic instr/wave spanning 2 cache lines (halves atomic traffic; r7 win).
__global__ __launch_bounds__(256) void agg_pool(const ushort_t* __restrict__ h,
                                                const int* __restrict__ csr_src,
                                                const int* __restrict__ cnt,
                                                const float* __restrict__ dinv,
                                                const int* __restrict__ batch,
                                                float* __restrict__ gsums) {
    int wv = threadIdx.x >> 6, lane = threadIdx.x & 63;
    int half, node;
    split_decode(blockIdx.x, wv, half, node);
    if (node >= N_NODES) return;
    int cg = lane >> 3;
    int cb = half * 64 + (lane & 7) * 8;

    float acc[8];
    agg_node_h(node, lane, cg, cb, h, csr_src, cnt, dinv, acc);  // no relu

    // static-index select of acc[cg] (avoid runtime-indexed array -> scratch)
    float val = acc[0];
#pragma unroll
    for (int t = 1; t < 8; ++t) if (cg == t) val = acc[t];

    int g = batch[node];
    unsafeAtomicAdd(gsums + (size_t)(blockIdx.x & (NREP - 1)) * (NUM_G * CH)
                          + g * CH + cb + cg, val);
}

// ---------------- final: fold 8 replicas, mean, @ Wp + bp --------------------
__global__ __launch_bounds__(128) void out_kernel(const float* __restrict__ gsums,
                                                  const int* __restrict__ counts,
                                                  const float* __restrict__ Wp,
                                                  const float* __restrict__ bp,
                                                  float* __restrict__ outp) {
    __shared__ float s_m[CH];
    int g = blockIdx.x, c = threadIdx.x;

    float acc = 0.0f;
#pragma unroll
    for (int r = 0; r < NREP; ++r)
        acc += gsums[(size_t)r * (NUM_G * CH) + g * CH + c];

    float inv = 1.0f / fmaxf((float)counts[g], 1.0f);
    s_m[c] = acc * inv;
    __syncthreads();

    if (c < OUT_CH) {
        float o = bp[c];
        for (int k = 0; k < CH; ++k)
            o = fmaf(s_m[k], Wp[k * OUT_CH + c], o);
        outp[g * OUT_CH + c] = o;
    }
}

extern "C" void kernel_launch(void* const* d_in, const int* in_sizes, int n_in,
                              void* d_out, int out_size, void* d_ws, size_t ws_size,
                              hipStream_t stream) {
    (void)in_sizes; (void)n_in; (void)out_size; (void)ws_size;
    const float* x     = (const float*)d_in[0];
    const int*   ei    = (const int*)d_in[1];
    const int*   batch = (const int*)d_in[2];
    const float* W1 = (const float*)d_in[3];
    const float* b1 = (const float*)d_in[4];
    const float* W2 = (const float*)d_in[5];
    const float* b2 = (const float*)d_in[6];
    const float* W3 = (const float*)d_in[7];
    const float* b3 = (const float*)d_in[8];
    const float* Wp = (const float*)d_in[9];
    const float* bp = (const float*)d_in[10];
    float* outp = (float*)d_out;

    const int* srcp = ei;
    const int* dstp = ei + N_EDGES;

    char* ws = (char*)d_ws;
    auto carve = [&](size_t bytes) {
        char* p = ws;
        ws += (bytes + 255) & ~(size_t)255;
        return p;
    };
    ushort_t* Hb = (ushort_t*)carve((size_t)N_NODES * CH * 2);  // 25.6 MB
    ushort_t* Ab = (ushort_t*)carve((size_t)N_NODES * CH * 2);  // 25.6 MB
    ushort_t* Wt1 = (ushort_t*)carve((size_t)CH * CH * 2);
    ushort_t* Wt2 = (ushort_t*)carve((size_t)CH * CH * 2);
    ushort_t* Wt3 = (ushort_t*)carve((size_t)CH * CH * 2);
    int*   csr_src  = (int*)carve((size_t)N_NODES * CAP * 4);   // 25.6 MB
    int*   cnt      = (int*)carve((size_t)N_NODES * 4);         // 400 KB
    float* dinv     = (float*)carve((size_t)N_NODES * 4);
    float* gsums    = (float*)carve((size_t)NREP * NUM_G * CH * 4);  // 256 KB
    int*   counts   = (int*)carve((size_t)NUM_G * 4);

    hipMemsetAsync(cnt,    0, (size_t)N_NODES * 4, stream);
    hipMemsetAsync(gsums,  0, (size_t)NREP * NUM_G * CH * 4, stream);
    hipMemsetAsync(counts, 0, (size_t)NUM_G * 4, stream);

    // W conversions first (Wt1 needed by prep_gemm1's GEMM half)
    cvtw_kernel<<<3 * WB, 256, 0, stream>>>(W1, W2, W3, Wt1, Wt2, Wt3);

    // direct CSR insert (count + slot + scatter in ONE atomic pass) | gemm1
    prep_gemm1<<<EB + GB, 256, 0, stream>>>(srcp, dstp, cnt, csr_src,
                                            x, Wt1, b1, Hb);

    dinv_kernel<<<DB, 1024, 0, stream>>>(cnt, dinv, batch, counts);

    agg_bf16 <<<AB, 256, 0, stream>>>(Hb, csr_src, cnt, dinv, Ab);
    // layer 2
    gemm_mfma<<<GB2, 512, 0, stream>>>(Ab, Wt2, b2, Hb);
    agg_bf16 <<<AB, 256, 0, stream>>>(Hb, csr_src, cnt, dinv, Ab);
    // layer 3: GEMM then aggregation fused with pooling (split, replica atomics)
    gemm_mfma<<<GB2, 512, 0, stream>>>(Ab, Wt3, b3, Hb);
    agg_pool <<<AB2, 256, 0, stream>>>(Hb, csr_src, cnt, dinv, batch, gsums);

    out_kernel<<<NUM_G, 128, 0, stream>>>(gsums, counts, Wp, bp, outp);
}

// Round 10
// 497.459 us; speedup vs baseline: 1.0869x; 1.0869x over previous
//
#include <hip/hip_runtime.h>

#define N_NODES 100000
#define N_EDGES 1600000
#define CH      128
#define OUT_CH  64
#define NUM_G   64
#define NREP    8           // gsums replicas (agg_pool atomics)
#define CAP     64          // fixed CSR slots per node (P(deg>64) ~ 2e-18)

typedef unsigned short ushort_t;
typedef unsigned int uint_t;
typedef __attribute__((ext_vector_type(8))) short short8;
typedef __attribute__((ext_vector_type(4))) float f32x4;

#define WB 64               // cvt_w blocks per weight (128*128/256)
#define EB 6250             // edge blocks, 1 edge/thread (prep)
#define EB8 782             // edge blocks, 8 edges/thread (fill)
#define GB ((N_NODES + 63) / 64)     // gemm1 row-blocks (64 rows/block)
#define GB2 ((N_NODES + 127) / 128)  // lds-gemm row-blocks (128 rows/block)
#define AB ((N_NODES + 3) / 4)       // agg node-quads (4 nodes/block)
#define AB2 (AB * 2)                 // channel-split agg_pool blocks
#define DB 98               // dinv blocks (ceil(100000/1024))

__device__ __forceinline__ ushort_t f2b(float f) {
    union { float f; uint_t i; } v; v.f = f;
    uint_t u = v.i;
    uint_t r = (u + 0x7fffu + ((u >> 16) & 1u)) >> 16;
    return (ushort_t)r;
}
__device__ __forceinline__ float blo(uint_t u) {
    union { uint_t i; float f; } v; v.i = u << 16; return v.f;
}
__device__ __forceinline__ float bhi(uint_t u) {
    union { uint_t i; float f; } v; v.i = u & 0xffff0000u; return v.f;
}

// ---------------- tiny pre-kernel: W1/W2/W3 f32 -> bf16 transposed -----------
__global__ __launch_bounds__(256) void cvtw_kernel(const float* __restrict__ W1,
                                                   const float* __restrict__ W2,
                                                   const float* __restrict__ W3,
                                                   ushort_t* __restrict__ Wt1,
                                                   ushort_t* __restrict__ Wt2,
                                                   ushort_t* __restrict__ Wt3) {
    int wi = blockIdx.x / WB;
    const float* W  = (wi == 0) ? W1 : (wi == 1) ? W2 : W3;
    ushort_t*   Wt = (wi == 0) ? Wt1 : (wi == 1) ? Wt2 : Wt3;
    int t = (blockIdx.x % WB) * 256 + threadIdx.x;
    int k = t >> 7, n = t & 127;
    Wt[(size_t)n * CH + k] = f2b(W[t]);
}

// ---------------- MFMA GEMM body, global-Wt flavor --------------------------
template <bool F32A>
__device__ __forceinline__ void gemm_body(int bid, int tid,
                                          const void* __restrict__ A,
                                          const ushort_t* __restrict__ Wt,
                                          const float* __restrict__ bias,
                                          ushort_t* __restrict__ H) {
    int wv = tid >> 6, lane = tid & 63;
    int q = lane >> 4, ml = lane & 15;
    int r0 = bid * 64 + wv * 16;
    int arow = r0 + ml;
    if (arow >= N_NODES) arow = N_NODES - 1;  // clamp; stores guarded

    f32x4 acc[8];
#pragma unroll
    for (int ct = 0; ct < 8; ++ct) { acc[ct][0] = 0.f; acc[ct][1] = 0.f; acc[ct][2] = 0.f; acc[ct][3] = 0.f; }

#pragma unroll
    for (int ks = 0; ks < 4; ++ks) {
        short8 af;
        if constexpr (F32A) {
            const float* ap = (const float*)A + (size_t)arow * CH + ks * 32 + q * 8;
            f32x4 v0 = *(const f32x4*)ap;
            f32x4 v1 = *(const f32x4*)(ap + 4);
#pragma unroll
            for (int j = 0; j < 4; ++j) {
                af[j]     = (short)f2b(v0[j]);
                af[j + 4] = (short)f2b(v1[j]);
            }
        } else {
            const ushort_t* ap = (const ushort_t*)A + (size_t)arow * CH + ks * 32 + q * 8;
            af = *(const short8*)ap;
        }
#pragma unroll
        for (int ct = 0; ct < 8; ++ct) {
            short8 bf = *(const short8*)(Wt + (size_t)(ct * 16 + ml) * CH + ks * 32 + q * 8);
            acc[ct] = __builtin_amdgcn_mfma_f32_16x16x32_bf16(af, bf, acc[ct], 0, 0, 0);
        }
    }

#pragma unroll
    for (int ct = 0; ct < 8; ++ct) {
        int col = ct * 16 + ml;
        float bv = bias[col];
#pragma unroll
        for (int i = 0; i < 4; ++i) {
            int rr = r0 + q * 4 + i;
            if (rr < N_NODES)
                H[(size_t)rr * CH + col] = f2b(acc[ct][i] + bv);
        }
    }
}

// ---------------- fused: degree count (+slot) | gemm layer-1 (fp32 A) --------
// r8 pattern: atomic + COALESCED pos store (no dependent random store -- r9's
// direct insert doubled latency exposure and line-sector write traffic).
// Single cnt array: slot is globally unique per node (needed for CAP layout).
__global__ __launch_bounds__(256) void prep_gemm1(const int* __restrict__ dst,
                                                  int* __restrict__ cnt,
                                                  int* __restrict__ pos,
                                                  const float* __restrict__ x,
                                                  const ushort_t* __restrict__ Wt,
                                                  const float* __restrict__ bias,
                                                  ushort_t* __restrict__ H) {
    if (blockIdx.x < EB) {
        int e = blockIdx.x * 256 + threadIdx.x;   // EB*256 == N_EDGES exactly
        pos[e] = atomicAdd(&cnt[dst[e]], 1);
    } else {
        gemm_body<true>(blockIdx.x - EB, threadIdx.x, x, Wt, bias, H);
    }
}

// ---------------- CSR scatter into fixed CAP-64 segments (no scan!) ----------
// 8 edges/thread for MLP; address is pure arithmetic dst*CAP+pos -- no random
// read per edge (r8's fill had a cnt8[d] gather; this one doesn't).
__global__ __launch_bounds__(256) void fill_kernel(const int* __restrict__ src,
                                                   const int* __restrict__ dst,
                                                   const int* __restrict__ pos,
                                                   int* __restrict__ csr_src) {
    int e = (blockIdx.x * 256 + threadIdx.x) * 8;
    if (e < N_EDGES) {     // N_EDGES % 8 == 0
        int4 da = *(const int4*)(dst + e);
        int4 db = *(const int4*)(dst + e + 4);
        int4 pa = *(const int4*)(pos + e);
        int4 pb = *(const int4*)(pos + e + 4);
        int4 sa = *(const int4*)(src + e);
        int4 sb = *(const int4*)(src + e + 4);
        if (pa.x < CAP) csr_src[(size_t)da.x * CAP + pa.x] = sa.x;
        if (pa.y < CAP) csr_src[(size_t)da.y * CAP + pa.y] = sa.y;
        if (pa.z < CAP) csr_src[(size_t)da.z * CAP + pa.z] = sa.z;
        if (pa.w < CAP) csr_src[(size_t)da.w * CAP + pa.w] = sa.w;
        if (pb.x < CAP) csr_src[(size_t)db.x * CAP + pb.x] = sb.x;
        if (pb.y < CAP) csr_src[(size_t)db.y * CAP + pb.y] = sb.y;
        if (pb.z < CAP) csr_src[(size_t)db.z * CAP + pb.z] = sb.z;
        if (pb.w < CAP) csr_src[(size_t)db.w * CAP + pb.w] = sb.w;
    }
}

// ---------------- dinv + graph-size histogram (replaces the scan chain) ------
__global__ __launch_bounds__(1024) void dinv_kernel(const int* __restrict__ cnt,
                                                    float* __restrict__ dinv,
                                                    const int* __restrict__ batch,
                                                    int* __restrict__ counts) {
    __shared__ int s_c[NUM_G];
    int tid = threadIdx.x;
    int i = blockIdx.x * 1024 + tid;
    if (tid < NUM_G) s_c[tid] = 0;
    __syncthreads();
    if (i < N_NODES) {
        dinv[i] = rsqrtf((float)cnt[i] + 1.0f);
        atomicAdd(&s_c[batch[i]], 1);
    }
    __syncthreads();
    if (tid < NUM_G) atomicAdd(&counts[tid], s_c[tid]);
}

// ---------------- standalone GEMM: Wt staged in LDS (XOR-swizzled) -----------
__global__ __launch_bounds__(512) void gemm_mfma(const ushort_t* __restrict__ A,
                                                 const ushort_t* __restrict__ Wt,
                                                 const float* __restrict__ bias,
                                                 ushort_t* __restrict__ H) {
    __shared__ ushort_t sW[CH * CH];   // 32 KiB
    int tid = threadIdx.x;
    for (int i = tid; i < CH * CH / 8; i += 512) {   // 2048 x 16B chunks
        int row = i >> 4, slot = i & 15;
        uint4 v = *(const uint4*)(Wt + (size_t)row * CH + slot * 8);
        *(uint4*)(&sW[row * CH + ((slot ^ (row & 7)) * 8)]) = v;
    }
    __syncthreads();

    int wv = tid >> 6, lane = tid & 63;
    int q = lane >> 4, ml = lane & 15;
    int r0 = blockIdx.x * 128 + wv * 16;
    int arow = r0 + ml;
    if (arow >= N_NODES) arow = N_NODES - 1;
    const ushort_t* ap = A + (size_t)arow * CH;

    f32x4 acc[8];
#pragma unroll
    for (int ct = 0; ct < 8; ++ct) { acc[ct][0] = 0.f; acc[ct][1] = 0.f; acc[ct][2] = 0.f; acc[ct][3] = 0.f; }

#pragma unroll
    for (int ks = 0; ks < 4; ++ks) {
        short8 af = *(const short8*)(ap + ks * 32 + q * 8);
        int slot = ks * 4 + q;
#pragma unroll
        for (int ct = 0; ct < 8; ++ct) {
            int srow = ct * 16 + ml;
            short8 bf = *(const short8*)(&sW[srow * CH + ((slot ^ (srow & 7)) * 8)]);
            acc[ct] = __builtin_amdgcn_mfma_f32_16x16x32_bf16(af, bf, acc[ct], 0, 0, 0);
        }
    }

#pragma unroll
    for (int ct = 0; ct < 8; ++ct) {
        int col = ct * 16 + ml;
        float bv = bias[col];
#pragma unroll
        for (int i = 0; i < 4; ++i) {
            int rr = r0 + q * 4 + i;
            if (rr < N_NODES)
                H[(size_t)rr * CH + col] = f2b(acc[ct][i] + bv);
        }
    }
}

// ---------------- UNSPLIT gather body (single <=64-edge chunk) ---------------
__device__ __forceinline__ void agg_node(int node, int lane, int q, int c8,
                                         const ushort_t* __restrict__ h,
                                         const int* __restrict__ csr_src,
                                         const int* __restrict__ cnt,
                                         const float* __restrict__ dinv,
                                         float (&acc)[8]) {
    int deg = min(cnt[node], CAP);
    float dn = dinv[node];
    uint4 us = *(const uint4*)(h + (size_t)node * CH + c8);   // early self load
#pragma unroll
    for (int i = 0; i < 8; ++i) acc[i] = 0.0f;

    int s = 0; float w = 0.0f;
    if (lane < deg) { s = csr_src[(size_t)node * CAP + lane]; w = dinv[s]; }

    if (deg > 0) {
        int   sj = __shfl(s, q);
        float wj = __shfl(w, q);
        uint4 u  = *(const uint4*)(h + (size_t)sj * CH + c8);

        for (int j0 = 0; j0 < deg; j0 += 4) {
            uint4 un = u; float wn = 0.0f;
            if (j0 + 4 < deg) {
                int sn = __shfl(s, j0 + 4 + q);
                wn = __shfl(w, j0 + 4 + q);
                un = *(const uint4*)(h + (size_t)sn * CH + c8);
            }
            acc[0] = fmaf(wj, blo(u.x), acc[0]);
            acc[1] = fmaf(wj, bhi(u.x), acc[1]);
            acc[2] = fmaf(wj, blo(u.y), acc[2]);
            acc[3] = fmaf(wj, bhi(u.y), acc[3]);
            acc[4] = fmaf(wj, blo(u.z), acc[4]);
            acc[5] = fmaf(wj, bhi(u.z), acc[5]);
            acc[6] = fmaf(wj, blo(u.w), acc[6]);
            acc[7] = fmaf(wj, bhi(u.w), acc[7]);
            u = un; wj = wn;
        }
    }

#pragma unroll
    for (int i = 0; i < 8; ++i) {
        acc[i] += __shfl_xor(acc[i], 16);
        acc[i] += __shfl_xor(acc[i], 32);
    }

    acc[0] = dn * fmaf(dn, blo(us.x), acc[0]);
    acc[1] = dn * fmaf(dn, bhi(us.x), acc[1]);
    acc[2] = dn * fmaf(dn, blo(us.y), acc[2]);
    acc[3] = dn * fmaf(dn, bhi(us.y), acc[3]);
    acc[4] = dn * fmaf(dn, blo(us.z), acc[4]);
    acc[5] = dn * fmaf(dn, bhi(us.z), acc[5]);
    acc[6] = dn * fmaf(dn, blo(us.w), acc[6]);
    acc[7] = dn * fmaf(dn, bhi(us.w), acc[7]);
}

// ---------------- edge aggregation, layers 1&2 (UNSPLIT; bf16 + relu) --------
__global__ __launch_bounds__(256) void agg_bf16(const ushort_t* __restrict__ h,
                                                const int* __restrict__ csr_src,
                                                const int* __restrict__ cnt,
                                                const float* __restrict__ dinv,
                                                ushort_t* __restrict__ outp) {
    int wv = threadIdx.x >> 6, lane = threadIdx.x & 63;
    int node = blockIdx.x * 4 + wv;
    if (node >= N_NODES) return;
    int q = lane >> 4;
    int c8 = (lane & 15) * 8;

    float acc[8];
    agg_node(node, lane, q, c8, h, csr_src, cnt, dinv, acc);

#pragma unroll
    for (int i = 0; i < 8; ++i) acc[i] = fmaxf(acc[i], 0.0f);   // relu

    if (q == 0) {
        uint4 o;
        o.x = (uint_t)f2b(acc[0]) | ((uint_t)f2b(acc[1]) << 16);
        o.y = (uint_t)f2b(acc[2]) | ((uint_t)f2b(acc[3]) << 16);
        o.z = (uint_t)f2b(acc[4]) | ((uint_t)f2b(acc[5]) << 16);
        o.w = (uint_t)f2b(acc[6]) | ((uint_t)f2b(acc[7]) << 16);
        *(uint4*)(outp + (size_t)node * CH + c8) = o;
    }
}

// ---------------- channel-split gather body (agg_pool only) ------------------
__device__ __forceinline__ void agg_node_h(int node, int lane, int cg, int cb,
                                           const ushort_t* __restrict__ h,
                                           const int* __restrict__ csr_src,
                                           const int* __restrict__ cnt,
                                           const float* __restrict__ dinv,
                                           float (&acc)[8]) {
    int deg = min(cnt[node], CAP);
    float dn = dinv[node];
    uint4 us = *(const uint4*)(h + (size_t)node * CH + cb);   // early self load
#pragma unroll
    for (int i = 0; i < 8; ++i) acc[i] = 0.0f;

    int s = 0; float w = 0.0f;
    if (lane < deg) { s = csr_src[(size_t)node * CAP + lane]; w = dinv[s]; }

    if (deg > 0) {
        int   sj = __shfl(s, cg);
        float wj = __shfl(w, cg);
        uint4 u  = *(const uint4*)(h + (size_t)sj * CH + cb);

        for (int j0 = 0; j0 < deg; j0 += 8) {
            uint4 un = u; float wn = 0.0f;
            if (j0 + 8 < deg) {                    // max shfl idx 48+8+7=63
                int sn = __shfl(s, j0 + 8 + cg);
                wn = __shfl(w, j0 + 8 + cg);
                un = *(const uint4*)(h + (size_t)sn * CH + cb);
            }
            acc[0] = fmaf(wj, blo(u.x), acc[0]);
            acc[1] = fmaf(wj, bhi(u.x), acc[1]);
            acc[2] = fmaf(wj, blo(u.y), acc[2]);
            acc[3] = fmaf(wj, bhi(u.y), acc[3]);
            acc[4] = fmaf(wj, blo(u.z), acc[4]);
            acc[5] = fmaf(wj, bhi(u.z), acc[5]);
            acc[6] = fmaf(wj, blo(u.w), acc[6]);
            acc[7] = fmaf(wj, bhi(u.w), acc[7]);
            u = un; wj = wn;
        }
    }

#pragma unroll
    for (int i = 0; i < 8; ++i) {          // sum over the 8 edge-slot groups
        acc[i] += __shfl_xor(acc[i], 8);
        acc[i] += __shfl_xor(acc[i], 16);
        acc[i] += __shfl_xor(acc[i], 32);
    }

    acc[0] = dn * fmaf(dn, blo(us.x), acc[0]);
    acc[1] = dn * fmaf(dn, bhi(us.x), acc[1]);
    acc[2] = dn * fmaf(dn, blo(us.y), acc[2]);
    acc[3] = dn * fmaf(dn, bhi(us.y), acc[3]);
    acc[4] = dn * fmaf(dn, blo(us.z), acc[4]);
    acc[5] = dn * fmaf(dn, bhi(us.z), acc[5]);
    acc[6] = dn * fmaf(dn, blo(us.w), acc[6]);
    acc[7] = dn * fmaf(dn, bhi(us.w), acc[7]);
}

__device__ __forceinline__ void split_decode(int b, int wv,
                                             int& half, int& node) {
    half = (b >> 2) & 1;
    int nb = ((b >> 3) << 2) | (b & 3);     // [0, AB)
    node = nb * 4 + wv;
}

// ---------------- layer-3 aggregation fused with mean-pool (SPLIT) -----------
__global__ __launch_bounds__(256) void agg_pool(const ushort_t* __restrict__ h,
                                                const int* __restrict__ csr_src,
                                                const int* __restrict__ cnt,
                                                const float* __restrict__ dinv,
                                                const int* __restrict__ batch,
                                                float* __restrict__ gsums) {
    int wv = threadIdx.x >> 6, lane = threadIdx.x & 63;
    int half, node;
    split_decode(blockIdx.x, wv, half, node);
    if (node >= N_NODES) return;
    int cg = lane >> 3;
    int cb = half * 64 + (lane & 7) * 8;

    float acc[8];
    agg_node_h(node, lane, cg, cb, h, csr_src, cnt, dinv, acc);  // no relu

    // static-index select of acc[cg] (avoid runtime-indexed array -> scratch)
    float val = acc[0];
#pragma unroll
    for (int t = 1; t < 8; ++t) if (cg == t) val = acc[t];

    int g = batch[node];
    unsafeAtomicAdd(gsums + (size_t)(blockIdx.x & (NREP - 1)) * (NUM_G * CH)
                          + g * CH + cb + cg, val);
}

// ---------------- final: fold 8 replicas, mean, @ Wp + bp --------------------
__global__ __launch_bounds__(128) void out_kernel(const float* __restrict__ gsums,
                                                  const int* __restrict__ counts,
                                                  const float* __restrict__ Wp,
                                                  const float* __restrict__ bp,
                                                  float* __restrict__ outp) {
    __shared__ float s_m[CH];
    int g = blockIdx.x, c = threadIdx.x;

    float acc = 0.0f;
#pragma unroll
    for (int r = 0; r < NREP; ++r)
        acc += gsums[(size_t)r * (NUM_G * CH) + g * CH + c];

    float inv = 1.0f / fmaxf((float)counts[g], 1.0f);
    s_m[c] = acc * inv;
    __syncthreads();

    if (c < OUT_CH) {
        float o = bp[c];
        for (int k = 0; k < CH; ++k)
            o = fmaf(s_m[k], Wp[k * OUT_CH + c], o);
        outp[g * OUT_CH + c] = o;
    }
}

extern "C" void kernel_launch(void* const* d_in, const int* in_sizes, int n_in,
                              void* d_out, int out_size, void* d_ws, size_t ws_size,
                              hipStream_t stream) {
    (void)in_sizes; (void)n_in; (void)out_size; (void)ws_size;
    const float* x     = (const float*)d_in[0];
    const int*   ei    = (const int*)d_in[1];
    const int*   batch = (const int*)d_in[2];
    const float* W1 = (const float*)d_in[3];
    const float* b1 = (const float*)d_in[4];
    const float* W2 = (const float*)d_in[5];
    const float* b2 = (const float*)d_in[6];
    const float* W3 = (const float*)d_in[7];
    const float* b3 = (const float*)d_in[8];
    const float* Wp = (const float*)d_in[9];
    const float* bp = (const float*)d_in[10];
    float* outp = (float*)d_out;

    const int* srcp = ei;
    const int* dstp = ei + N_EDGES;

    char* ws = (char*)d_ws;
    auto carve = [&](size_t bytes) {
        char* p = ws;
        ws += (bytes + 255) & ~(size_t)255;
        return p;
    };
    ushort_t* Hb = (ushort_t*)carve((size_t)N_NODES * CH * 2);  // 25.6 MB
    ushort_t* Ab = (ushort_t*)carve((size_t)N_NODES * CH * 2);  // 25.6 MB
    ushort_t* Wt1 = (ushort_t*)carve((size_t)CH * CH * 2);
    ushort_t* Wt2 = (ushort_t*)carve((size_t)CH * CH * 2);
    ushort_t* Wt3 = (ushort_t*)carve((size_t)CH * CH * 2);
    int*   csr_src  = (int*)carve((size_t)N_NODES * CAP * 4);   // 25.6 MB
    int*   pos      = (int*)carve((size_t)N_EDGES * 4);         // 6.4 MB
    int*   cnt      = (int*)carve((size_t)N_NODES * 4);         // 400 KB
    float* dinv     = (float*)carve((size_t)N_NODES * 4);
    float* gsums    = (float*)carve((size_t)NREP * NUM_G * CH * 4);  // 256 KB
    int*   counts   = (int*)carve((size_t)NUM_G * 4);

    hipMemsetAsync(cnt,    0, (size_t)N_NODES * 4, stream);
    hipMemsetAsync(gsums,  0, (size_t)NREP * NUM_G * CH * 4, stream);
    hipMemsetAsync(counts, 0, (size_t)NUM_G * 4, stream);

    // W conversions first (Wt1 needed by prep_gemm1's GEMM half)
    cvtw_kernel<<<3 * WB, 256, 0, stream>>>(W1, W2, W3, Wt1, Wt2, Wt3);

    // degree count + slot (coalesced pos store) overlapped with layer-1 GEMM
    prep_gemm1<<<EB + GB, 256, 0, stream>>>(dstp, cnt, pos, x, Wt1, b1, Hb);

    dinv_kernel<<<DB, 1024, 0, stream>>>(cnt, dinv, batch, counts);

    // CSR scatter into fixed CAP-64 segments (no scan chain)
    fill_kernel<<<EB8, 256, 0, stream>>>(srcp, dstp, pos, csr_src);

    agg_bf16 <<<AB, 256, 0, stream>>>(Hb, csr_src, cnt, dinv, Ab);
    // layer 2
    gemm_mfma<<<GB2, 512, 0, stream>>>(Ab, Wt2, b2, Hb);
    agg_bf16 <<<AB, 256, 0, stream>>>(Hb, csr_src, cnt, dinv, Ab);
    // layer 3: GEMM then aggregation fused with pooling (split, replica atomics)
    gemm_mfma<<<GB2, 512, 0, stream>>>(Ab, Wt3, b3, Hb);
    agg_pool <<<AB2, 256, 0, stream>>>(Hb, csr_src, cnt, dinv, batch, gsums);

    out_kernel<<<NUM_G, 128, 0, stream>>>(gsums, counts, Wp, bp, outp);
}

// Round 11
// 471.348 us; speedup vs baseline: 1.1471x; 1.0554x over previous
//
#include <hip/hip_runtime.h>

#define N_NODES 100000
#define N_EDGES 1600000
#define CH      128
#define OUT_CH  64
#define NUM_G   64
#define NREP    8           // gsums replicas (agg_pool atomics)
#define CAP     64          // fixed CSR slots per node (P(deg>64) ~ 2e-18)

typedef unsigned short ushort_t;
typedef unsigned int uint_t;
typedef __attribute__((ext_vector_type(8))) short short8;
typedef __attribute__((ext_vector_type(4))) float f32x4;

#define WB 64               // cvt_w blocks per weight (128*128/256)
#define ZC 98               // cnt-zero blocks (25000 uint4 / 256)
#define ZG 64               // gsums-zero blocks (16384 uint4 / 256)
#define EB 6250             // edge blocks, 1 edge/thread (prep)
#define EB8 782             // edge blocks, 8 edges/thread (fill)
#define DVB 391             // dinv blocks (ceil(100000/256))
#define GB ((N_NODES + 63) / 64)     // gemm1 row-blocks (64 rows/block)
#define GB2 ((N_NODES + 127) / 128)  // lds-gemm row-blocks (128 rows/block)
#define AB ((N_NODES + 3) / 4)       // agg node-quads (4 nodes/block)
#define AB2 (AB * 2)                 // channel-split agg_pool blocks

__device__ __forceinline__ ushort_t f2b(float f) {
    union { float f; uint_t i; } v; v.f = f;
    uint_t u = v.i;
    uint_t r = (u + 0x7fffu + ((u >> 16) & 1u)) >> 16;
    return (ushort_t)r;
}
__device__ __forceinline__ float blo(uint_t u) {
    union { uint_t i; float f; } v; v.i = u << 16; return v.f;
}
__device__ __forceinline__ float bhi(uint_t u) {
    union { uint_t i; float f; } v; v.i = u & 0xffff0000u; return v.f;
}

// ---------------- pre-kernel: W cvt + all workspace zeroing (no memsets) -----
__global__ __launch_bounds__(256) void cvtw_zero(const float* __restrict__ W1,
                                                 const float* __restrict__ W2,
                                                 const float* __restrict__ W3,
                                                 ushort_t* __restrict__ Wt1,
                                                 ushort_t* __restrict__ Wt2,
                                                 ushort_t* __restrict__ Wt3,
                                                 int* __restrict__ cnt,
                                                 float* __restrict__ gsums,
                                                 int* __restrict__ counts) {
    int b = blockIdx.x, tid = threadIdx.x;
    if (b < 3 * WB) {
        int wi = b / WB;
        const float* W  = (wi == 0) ? W1 : (wi == 1) ? W2 : W3;
        ushort_t*   Wt = (wi == 0) ? Wt1 : (wi == 1) ? Wt2 : Wt3;
        int t = (b % WB) * 256 + tid;
        int k = t >> 7, n = t & 127;
        Wt[(size_t)n * CH + k] = f2b(W[t]);
    } else if (b < 3 * WB + ZC) {
        int i = (b - 3 * WB) * 256 + tid;       // uint4 index into cnt
        if (i < (N_NODES * 4) / 16) ((uint4*)cnt)[i] = make_uint4(0, 0, 0, 0);
    } else if (b < 3 * WB + ZC + ZG) {
        int i = (b - 3 * WB - ZC) * 256 + tid;  // exactly 16384 uint4
        ((uint4*)gsums)[i] = make_uint4(0, 0, 0, 0);
    } else {
        if (tid < NUM_G) counts[tid] = 0;
    }
}

// ---------------- MFMA GEMM body, global-Wt flavor --------------------------
template <bool F32A>
__device__ __forceinline__ void gemm_body(int bid, int tid,
                                          const void* __restrict__ A,
                                          const ushort_t* __restrict__ Wt,
                                          const float* __restrict__ bias,
                                          ushort_t* __restrict__ H) {
    int wv = tid >> 6, lane = tid & 63;
    int q = lane >> 4, ml = lane & 15;
    int r0 = bid * 64 + wv * 16;
    int arow = r0 + ml;
    if (arow >= N_NODES) arow = N_NODES - 1;  // clamp; stores guarded

    f32x4 acc[8];
#pragma unroll
    for (int ct = 0; ct < 8; ++ct) { acc[ct][0] = 0.f; acc[ct][1] = 0.f; acc[ct][2] = 0.f; acc[ct][3] = 0.f; }

#pragma unroll
    for (int ks = 0; ks < 4; ++ks) {
        short8 af;
        if constexpr (F32A) {
            const float* ap = (const float*)A + (size_t)arow * CH + ks * 32 + q * 8;
            f32x4 v0 = *(const f32x4*)ap;
            f32x4 v1 = *(const f32x4*)(ap + 4);
#pragma unroll
            for (int j = 0; j < 4; ++j) {
                af[j]     = (short)f2b(v0[j]);
                af[j + 4] = (short)f2b(v1[j]);
            }
        } else {
            const ushort_t* ap = (const ushort_t*)A + (size_t)arow * CH + ks * 32 + q * 8;
            af = *(const short8*)ap;
        }
#pragma unroll
        for (int ct = 0; ct < 8; ++ct) {
            short8 bf = *(const short8*)(Wt + (size_t)(ct * 16 + ml) * CH + ks * 32 + q * 8);
            acc[ct] = __builtin_amdgcn_mfma_f32_16x16x32_bf16(af, bf, acc[ct], 0, 0, 0);
        }
    }

#pragma unroll
    for (int ct = 0; ct < 8; ++ct) {
        int col = ct * 16 + ml;
        float bv = bias[col];
#pragma unroll
        for (int i = 0; i < 4; ++i) {
            int rr = r0 + q * 4 + i;
            if (rr < N_NODES)
                H[(size_t)rr * CH + col] = f2b(acc[ct][i] + bv);
        }
    }
}

// ---------------- fused: gemm layer-1 FIRST | degree-count atomics -----------
// gemm blocks at the FRONT of the grid so they start at t=0 and finish inside
// the ~90us atomic phase's shadow (r10: gemm at the tail added ~22us).
__global__ __launch_bounds__(256) void prep_gemm1(const int* __restrict__ dst,
                                                  int* __restrict__ cnt,
                                                  int* __restrict__ pos,
                                                  const float* __restrict__ x,
                                                  const ushort_t* __restrict__ Wt,
                                                  const float* __restrict__ bias,
                                                  ushort_t* __restrict__ H) {
    if (blockIdx.x < GB) {
        gemm_body<true>(blockIdx.x, threadIdx.x, x, Wt, bias, H);
    } else {
        int e = (blockIdx.x - GB) * 256 + threadIdx.x;  // EB*256 == N_EDGES
        pos[e] = atomicAdd(&cnt[dst[e]], 1);
    }
}

// ---------------- CSR scatter into fixed CAP-64 segments | dinv+hist ---------
// 8 edges/thread for MLP; address is pure arithmetic dst*CAP+pos. dinv blocks
// ride along (streaming work overlaps the scatter's latency-bound blocks).
__global__ __launch_bounds__(256) void fill_dinv(const int* __restrict__ src,
                                                 const int* __restrict__ dst,
                                                 const int* __restrict__ pos,
                                                 int* __restrict__ csr_src,
                                                 const int* __restrict__ cnt,
                                                 float* __restrict__ dinv,
                                                 const int* __restrict__ batch,
                                                 int* __restrict__ counts) {
    if (blockIdx.x < EB8) {
        int e = (blockIdx.x * 256 + threadIdx.x) * 8;
        // N_EDGES % 8 == 0, always in range
        int4 da = *(const int4*)(dst + e);
        int4 db = *(const int4*)(dst + e + 4);
        int4 pa = *(const int4*)(pos + e);
        int4 pb = *(const int4*)(pos + e + 4);
        int4 sa = *(const int4*)(src + e);
        int4 sb = *(const int4*)(src + e + 4);
        if (pa.x < CAP) csr_src[(size_t)da.x * CAP + pa.x] = sa.x;
        if (pa.y < CAP) csr_src[(size_t)da.y * CAP + pa.y] = sa.y;
        if (pa.z < CAP) csr_src[(size_t)da.z * CAP + pa.z] = sa.z;
        if (pa.w < CAP) csr_src[(size_t)da.w * CAP + pa.w] = sa.w;
        if (pb.x < CAP) csr_src[(size_t)db.x * CAP + pb.x] = sb.x;
        if (pb.y < CAP) csr_src[(size_t)db.y * CAP + pb.y] = sb.y;
        if (pb.z < CAP) csr_src[(size_t)db.z * CAP + pb.z] = sb.z;
        if (pb.w < CAP) csr_src[(size_t)db.w * CAP + pb.w] = sb.w;
    } else {
        __shared__ int s_c[NUM_G];
        int tid = threadIdx.x;
        int i = (blockIdx.x - EB8) * 256 + tid;
        if (tid < NUM_G) s_c[tid] = 0;
        __syncthreads();
        if (i < N_NODES) {
            dinv[i] = rsqrtf((float)cnt[i] + 1.0f);
            atomicAdd(&s_c[batch[i]], 1);
        }
        __syncthreads();
        if (tid < NUM_G) atomicAdd(&counts[tid], s_c[tid]);
    }
}

// ---------------- standalone GEMM: Wt staged in LDS (XOR-swizzled) -----------
__global__ __launch_bounds__(512) void gemm_mfma(const ushort_t* __restrict__ A,
                                                 const ushort_t* __restrict__ Wt,
                                                 const float* __restrict__ bias,
                                                 ushort_t* __restrict__ H) {
    __shared__ ushort_t sW[CH * CH];   // 32 KiB
    int tid = threadIdx.x;
    for (int i = tid; i < CH * CH / 8; i += 512) {   // 2048 x 16B chunks
        int row = i >> 4, slot = i & 15;
        uint4 v = *(const uint4*)(Wt + (size_t)row * CH + slot * 8);
        *(uint4*)(&sW[row * CH + ((slot ^ (row & 7)) * 8)]) = v;
    }
    __syncthreads();

    int wv = tid >> 6, lane = tid & 63;
    int q = lane >> 4, ml = lane & 15;
    int r0 = blockIdx.x * 128 + wv * 16;
    int arow = r0 + ml;
    if (arow >= N_NODES) arow = N_NODES - 1;
    const ushort_t* ap = A + (size_t)arow * CH;

    f32x4 acc[8];
#pragma unroll
    for (int ct = 0; ct < 8; ++ct) { acc[ct][0] = 0.f; acc[ct][1] = 0.f; acc[ct][2] = 0.f; acc[ct][3] = 0.f; }

#pragma unroll
    for (int ks = 0; ks < 4; ++ks) {
        short8 af = *(const short8*)(ap + ks * 32 + q * 8);
        int slot = ks * 4 + q;
#pragma unroll
        for (int ct = 0; ct < 8; ++ct) {
            int srow = ct * 16 + ml;
            short8 bf = *(const short8*)(&sW[srow * CH + ((slot ^ (srow & 7)) * 8)]);
            acc[ct] = __builtin_amdgcn_mfma_f32_16x16x32_bf16(af, bf, acc[ct], 0, 0, 0);
        }
    }

#pragma unroll
    for (int ct = 0; ct < 8; ++ct) {
        int col = ct * 16 + ml;
        float bv = bias[col];
#pragma unroll
        for (int i = 0; i < 4; ++i) {
            int rr = r0 + q * 4 + i;
            if (rr < N_NODES)
                H[(size_t)rr * CH + col] = f2b(acc[ct][i] + bv);
        }
    }
}

// ---------------- UNSPLIT gather body (single <=64-edge chunk) ---------------
__device__ __forceinline__ void agg_node(int node, int lane, int q, int c8,
                                         const ushort_t* __restrict__ h,
                                         const int* __restrict__ csr_src,
                                         const int* __restrict__ cnt,
                                         const float* __restrict__ dinv,
                                         float (&acc)[8]) {
    int deg = min(cnt[node], CAP);
    float dn = dinv[node];
    uint4 us = *(const uint4*)(h + (size_t)node * CH + c8);   // early self load
#pragma unroll
    for (int i = 0; i < 8; ++i) acc[i] = 0.0f;

    int s = 0; float w = 0.0f;
    if (lane < deg) { s = csr_src[(size_t)node * CAP + lane]; w = dinv[s]; }

    if (deg > 0) {
        int   sj = __shfl(s, q);
        float wj = __shfl(w, q);
        uint4 u  = *(const uint4*)(h + (size_t)sj * CH + c8);

        for (int j0 = 0; j0 < deg; j0 += 4) {
            uint4 un = u; float wn = 0.0f;
            if (j0 + 4 < deg) {
                int sn = __shfl(s, j0 + 4 + q);
                wn = __shfl(w, j0 + 4 + q);
                un = *(const uint4*)(h + (size_t)sn * CH + c8);
            }
            acc[0] = fmaf(wj, blo(u.x), acc[0]);
            acc[1] = fmaf(wj, bhi(u.x), acc[1]);
            acc[2] = fmaf(wj, blo(u.y), acc[2]);
            acc[3] = fmaf(wj, bhi(u.y), acc[3]);
            acc[4] = fmaf(wj, blo(u.z), acc[4]);
            acc[5] = fmaf(wj, bhi(u.z), acc[5]);
            acc[6] = fmaf(wj, blo(u.w), acc[6]);
            acc[7] = fmaf(wj, bhi(u.w), acc[7]);
            u = un; wj = wn;
        }
    }

#pragma unroll
    for (int i = 0; i < 8; ++i) {
        acc[i] += __shfl_xor(acc[i], 16);
        acc[i] += __shfl_xor(acc[i], 32);
    }

    acc[0] = dn * fmaf(dn, blo(us.x), acc[0]);
    acc[1] = dn * fmaf(dn, bhi(us.x), acc[1]);
    acc[2] = dn * fmaf(dn, blo(us.y), acc[2]);
    acc[3] = dn * fmaf(dn, bhi(us.y), acc[3]);
    acc[4] = dn * fmaf(dn, blo(us.z), acc[4]);
    acc[5] = dn * fmaf(dn, bhi(us.z), acc[5]);
    acc[6] = dn * fmaf(dn, blo(us.w), acc[6]);
    acc[7] = dn * fmaf(dn, bhi(us.w), acc[7]);
}

// ---------------- edge aggregation, layers 1&2 (UNSPLIT; bf16 + relu) --------
__global__ __launch_bounds__(256) void agg_bf16(const ushort_t* __restrict__ h,
                                                const int* __restrict__ csr_src,
                                                const int* __restrict__ cnt,
                                                const float* __restrict__ dinv,
                                                ushort_t* __restrict__ outp) {
    int wv = threadIdx.x >> 6, lane = threadIdx.x & 63;
    int node = blockIdx.x * 4 + wv;
    if (node >= N_NODES) return;
    int q = lane >> 4;
    int c8 = (lane & 15) * 8;

    float acc[8];
    agg_node(node, lane, q, c8, h, csr_src, cnt, dinv, acc);

#pragma unroll
    for (int i = 0; i < 8; ++i) acc[i] = fmaxf(acc[i], 0.0f);   // relu

    if (q == 0) {
        uint4 o;
        o.x = (uint_t)f2b(acc[0]) | ((uint_t)f2b(acc[1]) << 16);
        o.y = (uint_t)f2b(acc[2]) | ((uint_t)f2b(acc[3]) << 16);
        o.z = (uint_t)f2b(acc[4]) | ((uint_t)f2b(acc[5]) << 16);
        o.w = (uint_t)f2b(acc[6]) | ((uint_t)f2b(acc[7]) << 16);
        *(uint4*)(outp + (size_t)node * CH + c8) = o;
    }
}

// ---------------- channel-split gather body (agg_pool only) ------------------
__device__ __forceinline__ void agg_node_h(int node, int lane, int cg, int cb,
                                           const ushort_t* __restrict__ h,
                                           const int* __restrict__ csr_src,
                                           const int* __restrict__ cnt,
                                           const float* __restrict__ dinv,
                                           float (&acc)[8]) {
    int deg = min(cnt[node], CAP);
    float dn = dinv[node];
    uint4 us = *(const uint4*)(h + (size_t)node * CH + cb);   // early self load
#pragma unroll
    for (int i = 0; i < 8; ++i) acc[i] = 0.0f;

    int s = 0; float w = 0.0f;
    if (lane < deg) { s = csr_src[(size_t)node * CAP + lane]; w = dinv[s]; }

    if (deg > 0) {
        int   sj = __shfl(s, cg);
        float wj = __shfl(w, cg);
        uint4 u  = *(const uint4*)(h + (size_t)sj * CH + cb);

        for (int j0 = 0; j0 < deg; j0 += 8) {
            uint4 un = u; float wn = 0.0f;
            if (j0 + 8 < deg) {                    // max shfl idx 48+8+7=63
                int sn = __shfl(s, j0 + 8 + cg);
                wn = __shfl(w, j0 + 8 + cg);
                un = *(const uint4*)(h + (size_t)sn * CH + cb);
            }
            acc[0] = fmaf(wj, blo(u.x), acc[0]);
            acc[1] = fmaf(wj, bhi(u.x), acc[1]);
            acc[2] = fmaf(wj, blo(u.y), acc[2]);
            acc[3] = fmaf(wj, bhi(u.y), acc[3]);
            acc[4] = fmaf(wj, blo(u.z), acc[4]);
            acc[5] = fmaf(wj, bhi(u.z), acc[5]);
            acc[6] = fmaf(wj, blo(u.w), acc[6]);
            acc[7] = fmaf(wj, bhi(u.w), acc[7]);
            u = un; wj = wn;
        }
    }

#pragma unroll
    for (int i = 0; i < 8; ++i) {          // sum over the 8 edge-slot groups
        acc[i] += __shfl_xor(acc[i], 8);
        acc[i] += __shfl_xor(acc[i], 16);
        acc[i] += __shfl_xor(acc[i], 32);
    }

    acc[0] = dn * fmaf(dn, blo(us.x), acc[0]);
    acc[1] = dn * fmaf(dn, bhi(us.x), acc[1]);
    acc[2] = dn * fmaf(dn, blo(us.y), acc[2]);
    acc[3] = dn * fmaf(dn, bhi(us.y), acc[3]);
    acc[4] = dn * fmaf(dn, blo(us.z), acc[4]);
    acc[5] = dn * fmaf(dn, bhi(us.z), acc[5]);
    acc[6] = dn * fmaf(dn, blo(us.w), acc[6]);
    acc[7] = dn * fmaf(dn, bhi(us.w), acc[7]);
}

__device__ __forceinline__ void split_decode(int b, int wv,
                                             int& half, int& node) {
    half = (b >> 2) & 1;
    int nb = ((b >> 3) << 2) | (b & 3);     // [0, AB)
    node = nb * 4 + wv;
}

// ---------------- layer-3 aggregation fused with mean-pool (SPLIT) -----------
__global__ __launch_bounds__(256) void agg_pool(const ushort_t* __restrict__ h,
                                                const int* __restrict__ csr_src,
                                                const int* __restrict__ cnt,
                                                const float* __restrict__ dinv,
                                                const int* __restrict__ batch,
                                                float* __restrict__ gsums) {
    int wv = threadIdx.x >> 6, lane = threadIdx.x & 63;
    int half, node;
    split_decode(blockIdx.x, wv, half, node);
    if (node >= N_NODES) return;
    int cg = lane >> 3;
    int cb = half * 64 + (lane & 7) * 8;

    float acc[8];
    agg_node_h(node, lane, cg, cb, h, csr_src, cnt, dinv, acc);  // no relu

    // static-index select of acc[cg] (avoid runtime-indexed array -> scratch)
    float val = acc[0];
#pragma unroll
    for (int t = 1; t < 8; ++t) if (cg == t) val = acc[t];

    int g = batch[node];
    unsafeAtomicAdd(gsums + (size_t)(blockIdx.x & (NREP - 1)) * (NUM_G * CH)
                          + g * CH + cb + cg, val);
}

// ---------------- final: fold 8 replicas, mean, @ Wp + bp --------------------
__global__ __launch_bounds__(128) void out_kernel(const float* __restrict__ gsums,
                                                  const int* __restrict__ counts,
                                                  const float* __restrict__ Wp,
                                                  const float* __restrict__ bp,
                                                  float* __restrict__ outp) {
    __shared__ float s_m[CH];
    int g = blockIdx.x, c = threadIdx.x;

    float acc = 0.0f;
#pragma unroll
    for (int r = 0; r < NREP; ++r)
        acc += gsums[(size_t)r * (NUM_G * CH) + g * CH + c];

    float inv = 1.0f / fmaxf((float)counts[g], 1.0f);
    s_m[c] = acc * inv;
    __syncthreads();

    if (c < OUT_CH) {
        float o = bp[c];
        for (int k = 0; k < CH; ++k)
            o = fmaf(s_m[k], Wp[k * OUT_CH + c], o);
        outp[g * OUT_CH + c] = o;
    }
}

extern "C" void kernel_launch(void* const* d_in, const int* in_sizes, int n_in,
                              void* d_out, int out_size, void* d_ws, size_t ws_size,
                              hipStream_t stream) {
    (void)in_sizes; (void)n_in; (void)out_size; (void)ws_size;
    const float* x     = (const float*)d_in[0];
    const int*   ei    = (const int*)d_in[1];
    const int*   batch = (const int*)d_in[2];
    const float* W1 = (const float*)d_in[3];
    const float* b1 = (const float*)d_in[4];
    const float* W2 = (const float*)d_in[5];
    const float* b2 = (const float*)d_in[6];
    const float* W3 = (const float*)d_in[7];
    const float* b3 = (const float*)d_in[8];
    const float* Wp = (const float*)d_in[9];
    const float* bp = (const float*)d_in[10];
    float* outp = (float*)d_out;

    const int* srcp = ei;
    const int* dstp = ei + N_EDGES;

    char* ws = (char*)d_ws;
    auto carve = [&](size_t bytes) {
        char* p = ws;
        ws += (bytes + 255) & ~(size_t)255;
        return p;
    };
    ushort_t* Hb = (ushort_t*)carve((size_t)N_NODES * CH * 2);  // 25.6 MB
    ushort_t* Ab = (ushort_t*)carve((size_t)N_NODES * CH * 2);  // 25.6 MB
    ushort_t* Wt1 = (ushort_t*)carve((size_t)CH * CH * 2);
    ushort_t* Wt2 = (ushort_t*)carve((size_t)CH * CH * 2);
    ushort_t* Wt3 = (ushort_t*)carve((size_t)CH * CH * 2);
    int*   csr_src  = (int*)carve((size_t)N_NODES * CAP * 4);   // 25.6 MB
    int*   pos      = (int*)carve((size_t)N_EDGES * 4);         // 6.4 MB
    int*   cnt      = (int*)carve((size_t)N_NODES * 4);         // 400 KB
    float* dinv     = (float*)carve((size_t)N_NODES * 4);
    float* gsums    = (float*)carve((size_t)NREP * NUM_G * CH * 4);  // 256 KB
    int*   counts   = (int*)carve((size_t)NUM_G * 4);

    // W conversions + workspace zeroing in one dispatch (no hipMemsetAsync)
    cvtw_zero<<<3 * WB + ZC + ZG + 1, 256, 0, stream>>>(W1, W2, W3,
                                                        Wt1, Wt2, Wt3,
                                                        cnt, gsums, counts);

    // layer-1 GEMM blocks FIRST, then the degree-count atomic flood
    prep_gemm1<<<GB + EB, 256, 0, stream>>>(dstp, cnt, pos, x, Wt1, b1, Hb);

    // CSR scatter into CAP-64 segments | dinv + graph-size histogram
    fill_dinv<<<EB8 + DVB, 256, 0, stream>>>(srcp, dstp, pos, csr_src,
                                             cnt, dinv, batch, counts);

    agg_bf16 <<<AB, 256, 0, stream>>>(Hb, csr_src, cnt, dinv, Ab);
    // layer 2
    gemm_mfma<<<GB2, 512, 0, stream>>>(Ab, Wt2, b2, Hb);
    agg_bf16 <<<AB, 256, 0, stream>>>(Hb, csr_src, cnt, dinv, Ab);
    // layer 3: GEMM then aggregation fused with pooling (split, replica atomics)
    gemm_mfma<<<GB2, 512, 0, stream>>>(Ab, Wt3, b3, Hb);
    agg_pool <<<AB2, 256, 0, stream>>>(Hb, csr_src, cnt, dinv, batch, gsums);

    out_kernel<<<NUM_G, 128, 0, stream>>>(gsums, counts, Wp, bp, outp);
}